// Round 1
// baseline (1266.640 us; speedup 1.0000x reference)
//
#include <hip/hip_runtime.h>
#include <cstddef>

#define HWN 65536              // 256*256
#define SCALE 0.35355339059327373f

// ---------------------------------------------------------------------------
// Kernel 1: 1x1 conv, 64 -> 64 channels.  y[b][o][p] = sum_c W[o][c] x[b][c][p]
// One thread per position; channel vector in registers; W via scalar loads.
// ---------------------------------------------------------------------------
__global__ __launch_bounds__(256) void conv1x1_64(
    const float* __restrict__ X, const float* __restrict__ W,
    float* __restrict__ Y)
{
    int gp = blockIdx.x * 256 + threadIdx.x;   // 0..131071
    int b  = gp >> 16;
    int p  = gp & 65535;
    const float* Xb = X + (size_t)b * 64 * HWN + p;
    float* Yb       = Y + (size_t)b * 64 * HWN + p;

    float xr[64];
#pragma unroll
    for (int c = 0; c < 64; c++) xr[c] = Xb[(size_t)c * HWN];

#pragma unroll 4
    for (int o = 0; o < 64; o++) {
        const float* Wr = W + o * 64;
        float acc = 0.f;
#pragma unroll
        for (int c = 0; c < 64; c++) acc = fmaf(Wr[c], xr[c], acc);
        Yb[(size_t)o * HWN] = acc;
    }
}

// ---------------------------------------------------------------------------
// Kernel 2: 1x1 conv, 256 -> 256 channels (GEMM).  Tile: 64 outputs x 64 pos.
// 256 threads, each computes 4x4.  K chunks of 64 staged in LDS.
// ---------------------------------------------------------------------------
__global__ __launch_bounds__(256) void conv1x1_256(
    const float* __restrict__ X, const float* __restrict__ W,
    float* __restrict__ Y)
{
    __shared__ float Wl[64 * 68];   // transposed: Wl[c'][o'] stride 68
    __shared__ float Xl[64 * 64];   // Xl[c'][p']

    int b  = blockIdx.z;
    int oB = blockIdx.y * 64;
    int pB = blockIdx.x * 64;
    int tid = threadIdx.x;
    int tx = tid & 15, ty = tid >> 4;

    const float* Xb = X + (size_t)b * 256 * HWN;
    float acc[4][4] = {};

    for (int kc = 0; kc < 256; kc += 64) {
#pragma unroll
        for (int s = 0; s < 16; s++) {
            int li = tid + s * 256;      // 0..4095
            int i = li >> 6;             // 0..63
            int j = li & 63;             // 0..63
            Wl[j * 68 + i] = W[(oB + i) * 256 + kc + j];
            Xl[i * 64 + j] = Xb[(size_t)(kc + i) * HWN + pB + j];
        }
        __syncthreads();
#pragma unroll
        for (int kk = 0; kk < 64; kk++) {
            float4 aw = *(const float4*)&Wl[kk * 68 + ty * 4];
            float4 bx = *(const float4*)&Xl[kk * 64 + tx * 4];
            acc[0][0] = fmaf(aw.x, bx.x, acc[0][0]);
            acc[0][1] = fmaf(aw.x, bx.y, acc[0][1]);
            acc[0][2] = fmaf(aw.x, bx.z, acc[0][2]);
            acc[0][3] = fmaf(aw.x, bx.w, acc[0][3]);
            acc[1][0] = fmaf(aw.y, bx.x, acc[1][0]);
            acc[1][1] = fmaf(aw.y, bx.y, acc[1][1]);
            acc[1][2] = fmaf(aw.y, bx.z, acc[1][2]);
            acc[1][3] = fmaf(aw.y, bx.w, acc[1][3]);
            acc[2][0] = fmaf(aw.z, bx.x, acc[2][0]);
            acc[2][1] = fmaf(aw.z, bx.y, acc[2][1]);
            acc[2][2] = fmaf(aw.z, bx.z, acc[2][2]);
            acc[2][3] = fmaf(aw.z, bx.w, acc[2][3]);
            acc[3][0] = fmaf(aw.w, bx.x, acc[3][0]);
            acc[3][1] = fmaf(aw.w, bx.y, acc[3][1]);
            acc[3][2] = fmaf(aw.w, bx.z, acc[3][2]);
            acc[3][3] = fmaf(aw.w, bx.w, acc[3][3]);
        }
        __syncthreads();
    }

#pragma unroll
    for (int i = 0; i < 4; i++) {
        float4 r = make_float4(acc[i][0], acc[i][1], acc[i][2], acc[i][3]);
        *(float4*)&Y[((size_t)b * 256 + oB + ty * 4 + i) * HWN + pB + tx * 4] = r;
    }
}

// ---------------------------------------------------------------------------
// Kernel 3: windowed attention.  One block (64 threads = 1 wave) per
// (window, head).  Thread n owns token n (n = ws1*8 + ws2).
// Reads QP,KP,VP; writes attention output to OUT (same NCHW layout as VP).
// ---------------------------------------------------------------------------
__global__ __launch_bounds__(64) void win_attn(
    const float* __restrict__ QP, const float* __restrict__ KP,
    const float* __restrict__ VP, float* __restrict__ OUT,
    const float* __restrict__ bias_table, const int* __restrict__ rel_index)
{
    __shared__ float kl[64 * 8];    // kl[m][d]
    __shared__ float vl[64 * 36];   // vl[m][d], padded stride 36

    int bx   = blockIdx.x;          // 0..16383
    int head = bx & 7;
    int win  = bx >> 3;
    int wc   = win & 31;
    int wr   = (win >> 5) & 31;
    int b    = win >> 10;

    int n   = threadIdx.x;          // token 0..63
    int ws1 = n >> 3, ws2 = n & 7;
    int pos = (wr * 8 + ws1) * 256 + wc * 8 + ws2;

    const float* qb = QP + ((size_t)(b * 64 + head * 8)) * HWN + pos;
    const float* kb = KP + ((size_t)(b * 64 + head * 8)) * HWN + pos;
    const float* vb = VP + ((size_t)(b * 256 + head * 32)) * HWN + pos;
    float*       ob = OUT + ((size_t)(b * 256 + head * 32)) * HWN + pos;

    float qr[8];
#pragma unroll
    for (int d = 0; d < 8; d++) {
        qr[d] = qb[(size_t)d * HWN];
        kl[n * 8 + d] = kb[(size_t)d * HWN];
    }
#pragma unroll
    for (int d = 0; d < 32; d++) vl[n * 36 + d] = vb[(size_t)d * HWN];
    __syncthreads();

    const int* ri = rel_index + n * 64;
    float attn[64];
    float mx = -1e30f;
#pragma unroll
    for (int m = 0; m < 64; m++) {
        float s = 0.f;
#pragma unroll
        for (int d = 0; d < 8; d++) s = fmaf(qr[d], kl[m * 8 + d], s);
        s = fmaf(s, SCALE, bias_table[ri[m] * 8 + head]);
        attn[m] = s;
        mx = fmaxf(mx, s);
    }
    float sum = 0.f;
#pragma unroll
    for (int m = 0; m < 64; m++) {
        float e = __expf(attn[m] - mx);
        attn[m] = e;
        sum += e;
    }
    float rs = 1.f / sum;
#pragma unroll
    for (int m = 0; m < 64; m++) attn[m] *= rs;

    // out[n][d] = sum_m attn[m] * v[m][d]
#pragma unroll
    for (int d4 = 0; d4 < 8; d4++) {
        float4 a = {0.f, 0.f, 0.f, 0.f};
#pragma unroll
        for (int m = 0; m < 64; m++) {
            float4 vv = *(const float4*)&vl[m * 36 + d4 * 4];
            a.x = fmaf(attn[m], vv.x, a.x);
            a.y = fmaf(attn[m], vv.y, a.y);
            a.z = fmaf(attn[m], vv.z, a.z);
            a.w = fmaf(attn[m], vv.w, a.w);
        }
        ob[(size_t)(d4 * 4 + 0) * HWN] = a.x;
        ob[(size_t)(d4 * 4 + 1) * HWN] = a.y;
        ob[(size_t)(d4 * 4 + 2) * HWN] = a.z;
        ob[(size_t)(d4 * 4 + 3) * HWN] = a.w;
    }
}

// ---------------------------------------------------------------------------
// Kernel 4: reflect-pad(0,1)x(0,1) + 8x8 depthwise conv (zero pad 3) + BN.
// Block = (b, channel, 32x32 tile).  Each thread computes a 1x4 x-strip with
// a register sliding window (11 LDS reads per tap-row instead of 32).
// ---------------------------------------------------------------------------
__global__ __launch_bounds__(256) void dwconv_bn(
    const float* __restrict__ A, const float* __restrict__ DW,
    const float* __restrict__ gamma, const float* __restrict__ beta,
    const float* __restrict__ mean, const float* __restrict__ var,
    float* __restrict__ O)
{
    __shared__ float til[39 * 40];

    int c  = blockIdx.y;
    int b  = blockIdx.z;
    int tY = (blockIdx.x >> 3) * 32;
    int tX = (blockIdx.x & 7) * 32;
    int tid = threadIdx.x;

    const float* Ab = A + ((size_t)(b * 256 + c)) * HWN;

    // Load 39x39 halo tile.  Logical padded coords: i in [-3,259];
    // zeros outside [0,256]; i==256 reflects to row/col 254.
    for (int li = tid; li < 39 * 39; li += 256) {
        int r  = li / 39, cc = li - r * 39;
        int iy = tY - 3 + r;
        int ix = tX - 3 + cc;
        float v = 0.f;
        if (iy >= 0 && iy <= 256 && ix >= 0 && ix <= 256) {
            int sy = (iy == 256) ? 254 : iy;
            int sx = (ix == 256) ? 254 : ix;
            v = Ab[sy * 256 + sx];
        }
        til[r * 40 + cc] = v;
    }
    __syncthreads();

    float inv = gamma[c] * rsqrtf(var[c] + 1e-5f);
    float add = fmaf(-mean[c], inv, beta[c]);

    int sx = (tid & 7) * 4;      // strip start col within tile
    int sy = tid >> 3;           // row within tile
    const float* dwc = DW + c * 64;

    float a0 = 0.f, a1 = 0.f, a2 = 0.f, a3 = 0.f;
#pragma unroll
    for (int ky = 0; ky < 8; ky++) {
        float row[11];
#pragma unroll
        for (int t = 0; t < 11; t++) row[t] = til[(sy + ky) * 40 + sx + t];
#pragma unroll
        for (int kx = 0; kx < 8; kx++) {
            float w = dwc[ky * 8 + kx];   // uniform -> scalar load
            a0 = fmaf(row[kx + 0], w, a0);
            a1 = fmaf(row[kx + 1], w, a1);
            a2 = fmaf(row[kx + 2], w, a2);
            a3 = fmaf(row[kx + 3], w, a3);
        }
    }

    float4 r = make_float4(fmaf(a0, inv, add), fmaf(a1, inv, add),
                           fmaf(a2, inv, add), fmaf(a3, inv, add));
    *(float4*)&O[((size_t)(b * 256 + c)) * HWN + (tY + sy) * 256 + tX + sx] = r;
}

// ---------------------------------------------------------------------------
// Launch.  Workspace layout (192 MiB):
//   qp : 2*64*65536 floats   (32 MiB)
//   kp : 2*64*65536 floats   (32 MiB)
//   vp : 2*256*65536 floats  (128 MiB)  -- reused as dw output after attention
// Attention writes into d_out; dwconv reads d_out, writes vp region (dead);
// pw conv reads that and writes final d_out.
// ---------------------------------------------------------------------------
extern "C" void kernel_launch(void* const* d_in, const int* in_sizes, int n_in,
                              void* d_out, int out_size, void* d_ws, size_t ws_size,
                              hipStream_t stream)
{
    (void)in_sizes; (void)n_in; (void)out_size; (void)ws_size;

    const float* q    = (const float*)d_in[0];
    const float* v    = (const float*)d_in[1];
    const float* Wq   = (const float*)d_in[2];
    const float* Wk   = (const float*)d_in[3];
    const float* Wv   = (const float*)d_in[4];
    const float* bt   = (const float*)d_in[5];
    const float* dw   = (const float*)d_in[6];
    const float* gam  = (const float*)d_in[7];
    const float* bet  = (const float*)d_in[8];
    const float* mean = (const float*)d_in[9];
    const float* var  = (const float*)d_in[10];
    const float* pw   = (const float*)d_in[11];
    const int*   ri   = (const int*)d_in[12];
    float* out = (float*)d_out;

    float* qp  = (float*)d_ws;
    float* kp  = qp + (size_t)2 * 64 * HWN;
    float* vp  = kp + (size_t)2 * 64 * HWN;
    float* dwo = vp;   // aliases vp: vp is dead once dwconv_bn runs

    conv1x1_64 <<<512, 256, 0, stream>>>(q, Wq, qp);
    conv1x1_64 <<<512, 256, 0, stream>>>(qp, Wk, kp);
    conv1x1_256<<<dim3(1024, 4, 2), 256, 0, stream>>>(v, Wv, vp);
    win_attn   <<<16384, 64, 0, stream>>>(qp, kp, vp, out, bt, ri);
    dwconv_bn  <<<dim3(64, 256, 2), 256, 0, stream>>>(out, dw, gam, bet, mean, var, dwo);
    conv1x1_256<<<dim3(1024, 4, 2), 256, 0, stream>>>(dwo, pw, out);
}

// Round 2
// 765.433 us; speedup vs baseline: 1.6548x; 1.6548x over previous
//
#include <hip/hip_runtime.h>
#include <cstddef>

#define HWN 65536              // 256*256
#define SCALE 0.35355339059327373f

typedef __bf16 bf16x8_t __attribute__((ext_vector_type(8)));
typedef float  f32x4_t  __attribute__((ext_vector_type(4)));

static __device__ __forceinline__ ushort f2bf(float f) {
    uint u = __float_as_uint(f);
    u = u + 0x7fffu + ((u >> 16) & 1u);   // RNE
    return (ushort)(u >> 16);
}
static __device__ __forceinline__ float bf2f(ushort b) {
    return __uint_as_float(((uint)b) << 16);
}

// ---------------------------------------------------------------------------
// Kernel 1: 1x1 conv, 64 -> 64 channels (fp32, VALU).
// ---------------------------------------------------------------------------
__global__ __launch_bounds__(256) void conv1x1_64(
    const float* __restrict__ X, const float* __restrict__ W,
    float* __restrict__ Y)
{
    int gp = blockIdx.x * 256 + threadIdx.x;
    int b  = gp >> 16;
    int p  = gp & 65535;
    const float* Xb = X + (size_t)b * 64 * HWN + p;
    float* Yb       = Y + (size_t)b * 64 * HWN + p;

    float xr[64];
#pragma unroll
    for (int c = 0; c < 64; c++) xr[c] = Xb[(size_t)c * HWN];

#pragma unroll 4
    for (int o = 0; o < 64; o++) {
        const float* Wr = W + o * 64;
        float acc = 0.f;
#pragma unroll
        for (int c = 0; c < 64; c++) acc = fmaf(Wr[c], xr[c], acc);
        Yb[(size_t)o * HWN] = acc;
    }
}

// ---------------------------------------------------------------------------
// Kernel 2: 256->256 channel GEMM via bf16 MFMA.
// Y[b][o][p] = sum_c W[o][c] X[b][c][p].  M=256(o), K=256(c), N=65536(p)/batch.
// Block: 256 thr = 4 waves (2x2), tile 128(M) x 128(N), BK=64.
// A (W) staged [m][k] bf16; B (X) staged transposed [n][k] bf16 with XOR
// swizzle on 16B k-groups so both frag reads are conflict-free ds_read_b128.
// fp32->bf16 conversion fused into staging (XT=float) or passthrough (ushort).
// ---------------------------------------------------------------------------
template <typename XT, typename YT>
__global__ __launch_bounds__(256) void gemm256(
    const XT* __restrict__ X, const float* __restrict__ W, YT* __restrict__ Y)
{
    __shared__ ushort Al[128 * 72];   // [m][k], stride 72 bf16 (144 B)
    __shared__ ushort Bl[128 * 72];   // [n][k], swizzled 16B groups

    int b   = blockIdx.z;
    int oB  = blockIdx.y * 128;
    int pB  = blockIdx.x * 128;
    int tid = threadIdx.x;

    const XT* Xb = X + (size_t)b * 256 * HWN;
    YT*       Yb = Y + (size_t)b * 256 * HWN;

    int wv = tid >> 6, lane = tid & 63;
    int wm = (wv >> 1) * 64, wn = (wv & 1) * 64;
    int qd = lane >> 4, ln = lane & 15;

    int kgB = tid >> 4;        // 0..15 -> k0 = kgB*4
    int pgB = tid & 15;        // 0..15 -> p0 = pgB*8
    int p0  = pgB * 8;

    f32x4_t acc[4][4];
#pragma unroll
    for (int i = 0; i < 4; i++)
#pragma unroll
        for (int j = 0; j < 4; j++) acc[i][j] = {0.f, 0.f, 0.f, 0.f};

    for (int kc = 0; kc < 256; kc += 64) {
        // ---- stage A: W[oB..+128][kc..+64] -> Al[m][k] (bf16) ----
#pragma unroll
        for (int s = 0; s < 4; s++) {
            int u = tid + s * 256;        // 0..1023 units of 8
            int m = u >> 3, kg = u & 7;
            const float4* src = (const float4*)&W[(oB + m) * 256 + kc + kg * 8];
            float4 w0 = src[0], w1 = src[1];
            uint4 pk;
            pk.x = f2bf(w0.x) | ((uint)f2bf(w0.y) << 16);
            pk.y = f2bf(w0.z) | ((uint)f2bf(w0.w) << 16);
            pk.z = f2bf(w1.x) | ((uint)f2bf(w1.y) << 16);
            pk.w = f2bf(w1.z) | ((uint)f2bf(w1.w) << 16);
            *(uint4*)&Al[m * 72 + kg * 8] = pk;
        }
        // ---- stage B: X[kc..+64][pB..+128] -> Bl[n][k] transposed ----
        ushort r[4][8];
#pragma unroll
        for (int i = 0; i < 4; i++) {
            int c = kc + kgB * 4 + i;
            if constexpr (sizeof(XT) == 4) {
                const float4* s = (const float4*)&Xb[(size_t)c * HWN + pB + p0];
                float4 x0 = s[0], x1 = s[1];
                r[i][0] = f2bf(x0.x); r[i][1] = f2bf(x0.y);
                r[i][2] = f2bf(x0.z); r[i][3] = f2bf(x0.w);
                r[i][4] = f2bf(x1.x); r[i][5] = f2bf(x1.y);
                r[i][6] = f2bf(x1.z); r[i][7] = f2bf(x1.w);
            } else {
                uint4 u = *(const uint4*)&Xb[(size_t)c * HWN + pB + p0];
                r[i][0] = u.x & 0xffff; r[i][1] = u.x >> 16;
                r[i][2] = u.y & 0xffff; r[i][3] = u.y >> 16;
                r[i][4] = u.z & 0xffff; r[i][5] = u.z >> 16;
                r[i][6] = u.w & 0xffff; r[i][7] = u.w >> 16;
            }
        }
        {
            int g   = kgB >> 1;           // 16B group index of k0
            int sub = (kgB & 1) * 4;      // offset within group
#pragma unroll
            for (int j = 0; j < 8; j++) {
                int n = p0 + j;
                ushort4 col = make_ushort4(r[0][j], r[1][j], r[2][j], r[3][j]);
                *(ushort4*)&Bl[n * 72 + ((g ^ (pgB & 7)) << 3) + sub] = col;
            }
        }
        __syncthreads();

        // ---- MFMA over this K-chunk ----
#pragma unroll
        for (int ks = 0; ks < 2; ks++) {
            bf16x8_t af[4], bf[4];
#pragma unroll
            for (int i = 0; i < 4; i++)
                af[i] = *(const bf16x8_t*)&Al[(wm + i * 16 + ln) * 72 + ks * 32 + qd * 8];
#pragma unroll
            for (int j = 0; j < 4; j++) {
                int n = wn + j * 16 + ln;
                int g = ks * 4 + qd;
                bf[j] = *(const bf16x8_t*)&Bl[n * 72 + ((g ^ ((n >> 3) & 7)) << 3)];
            }
#pragma unroll
            for (int i = 0; i < 4; i++)
#pragma unroll
                for (int j = 0; j < 4; j++)
                    acc[i][j] = __builtin_amdgcn_mfma_f32_16x16x32_bf16(
                        af[i], bf[j], acc[i][j], 0, 0, 0);
        }
        __syncthreads();
    }

    // ---- epilogue: D[row=qd*4+r][col=ln] per 16x16 frag ----
#pragma unroll
    for (int i = 0; i < 4; i++) {
#pragma unroll
        for (int j = 0; j < 4; j++) {
#pragma unroll
            for (int rr = 0; rr < 4; rr++) {
                int o = oB + wm + i * 16 + qd * 4 + rr;
                int p = pB + wn + j * 16 + ln;
                if constexpr (sizeof(YT) == 4)
                    Yb[(size_t)o * HWN + p] = acc[i][j][rr];
                else
                    Yb[(size_t)o * HWN + p] = f2bf(acc[i][j][rr]);
            }
        }
    }
}

// ---------------------------------------------------------------------------
// Kernel 3: windowed attention.  One wave per (window, head).
// Q,K fp32; V bf16 in, out bf16.  OUT may alias VP (identical address set per
// block; all VP reads complete before the barrier, stores after).
// ---------------------------------------------------------------------------
__global__ __launch_bounds__(64) void win_attn(
    const float* __restrict__ QP, const float* __restrict__ KP,
    const ushort* VP, ushort* OUT,
    const float* __restrict__ bias_table, const int* __restrict__ rel_index)
{
    __shared__ float kl[64 * 8];
    __shared__ float vl[64 * 36];

    int bx   = blockIdx.x;
    int head = bx & 7;
    int win  = bx >> 3;
    int wc   = win & 31;
    int wr   = (win >> 5) & 31;
    int b    = win >> 10;

    int n   = threadIdx.x;
    int ws1 = n >> 3, ws2 = n & 7;
    int pos = (wr * 8 + ws1) * 256 + wc * 8 + ws2;

    const float*  qb = QP + ((size_t)(b * 64 + head * 8)) * HWN + pos;
    const float*  kb = KP + ((size_t)(b * 64 + head * 8)) * HWN + pos;
    const ushort* vb = VP + ((size_t)(b * 256 + head * 32)) * HWN + pos;
    ushort*       ob = OUT + ((size_t)(b * 256 + head * 32)) * HWN + pos;

    float qr[8];
#pragma unroll
    for (int d = 0; d < 8; d++) {
        qr[d] = qb[(size_t)d * HWN];
        kl[n * 8 + d] = kb[(size_t)d * HWN];
    }
#pragma unroll
    for (int d = 0; d < 32; d++) vl[n * 36 + d] = bf2f(vb[(size_t)d * HWN]);
    __syncthreads();

    const int* ri = rel_index + n * 64;
    float attn[64];
    float mx = -1e30f;
#pragma unroll
    for (int m = 0; m < 64; m++) {
        float s = 0.f;
#pragma unroll
        for (int d = 0; d < 8; d++) s = fmaf(qr[d], kl[m * 8 + d], s);
        s = fmaf(s, SCALE, bias_table[ri[m] * 8 + head]);
        attn[m] = s;
        mx = fmaxf(mx, s);
    }
    float sum = 0.f;
#pragma unroll
    for (int m = 0; m < 64; m++) {
        float e = __expf(attn[m] - mx);
        attn[m] = e;
        sum += e;
    }
    float rs = 1.f / sum;
#pragma unroll
    for (int m = 0; m < 64; m++) attn[m] *= rs;

#pragma unroll
    for (int d4 = 0; d4 < 8; d4++) {
        float4 a = {0.f, 0.f, 0.f, 0.f};
#pragma unroll
        for (int m = 0; m < 64; m++) {
            float4 vv = *(const float4*)&vl[m * 36 + d4 * 4];
            a.x = fmaf(attn[m], vv.x, a.x);
            a.y = fmaf(attn[m], vv.y, a.y);
            a.z = fmaf(attn[m], vv.z, a.z);
            a.w = fmaf(attn[m], vv.w, a.w);
        }
        ob[(size_t)(d4 * 4 + 0) * HWN] = f2bf(a.x);
        ob[(size_t)(d4 * 4 + 1) * HWN] = f2bf(a.y);
        ob[(size_t)(d4 * 4 + 2) * HWN] = f2bf(a.z);
        ob[(size_t)(d4 * 4 + 3) * HWN] = f2bf(a.w);
    }
}

// ---------------------------------------------------------------------------
// Kernel 4: reflect-pad + 8x8 depthwise conv + BN.  bf16 in/out, fp32 math.
// ---------------------------------------------------------------------------
__global__ __launch_bounds__(256) void dwconv_bn(
    const ushort* __restrict__ A, const float* __restrict__ DW,
    const float* __restrict__ gamma, const float* __restrict__ beta,
    const float* __restrict__ mean, const float* __restrict__ var,
    ushort* __restrict__ O)
{
    __shared__ float til[39 * 40];

    int c  = blockIdx.y;
    int b  = blockIdx.z;
    int tY = (blockIdx.x >> 3) * 32;
    int tX = (blockIdx.x & 7) * 32;
    int tid = threadIdx.x;

    const ushort* Ab = A + ((size_t)(b * 256 + c)) * HWN;

    for (int li = tid; li < 39 * 39; li += 256) {
        int r  = li / 39, cc = li - r * 39;
        int iy = tY - 3 + r;
        int ix = tX - 3 + cc;
        float v = 0.f;
        if (iy >= 0 && iy <= 256 && ix >= 0 && ix <= 256) {
            int sy = (iy == 256) ? 254 : iy;
            int sx = (ix == 256) ? 254 : ix;
            v = bf2f(Ab[sy * 256 + sx]);
        }
        til[r * 40 + cc] = v;
    }
    __syncthreads();

    float inv = gamma[c] * rsqrtf(var[c] + 1e-5f);
    float add = fmaf(-mean[c], inv, beta[c]);

    int sx = (tid & 7) * 4;
    int sy = tid >> 3;
    const float* dwc = DW + c * 64;

    float a0 = 0.f, a1 = 0.f, a2 = 0.f, a3 = 0.f;
#pragma unroll
    for (int ky = 0; ky < 8; ky++) {
        float row[11];
#pragma unroll
        for (int t = 0; t < 11; t++) row[t] = til[(sy + ky) * 40 + sx + t];
#pragma unroll
        for (int kx = 0; kx < 8; kx++) {
            float w = dwc[ky * 8 + kx];
            a0 = fmaf(row[kx + 0], w, a0);
            a1 = fmaf(row[kx + 1], w, a1);
            a2 = fmaf(row[kx + 2], w, a2);
            a3 = fmaf(row[kx + 3], w, a3);
        }
    }

    ushort4 r4 = make_ushort4(f2bf(fmaf(a0, inv, add)), f2bf(fmaf(a1, inv, add)),
                              f2bf(fmaf(a2, inv, add)), f2bf(fmaf(a3, inv, add)));
    *(ushort4*)&O[((size_t)(b * 256 + c)) * HWN + (tY + sy) * 256 + tX + sx] = r4;
}

// ---------------------------------------------------------------------------
// Workspace (192 MiB total):
//   qp  fp32  32 MiB | kp fp32 32 MiB | vp bf16 64 MiB (aliased by attn out)
//   dwo bf16  64 MiB
// ---------------------------------------------------------------------------
extern "C" void kernel_launch(void* const* d_in, const int* in_sizes, int n_in,
                              void* d_out, int out_size, void* d_ws, size_t ws_size,
                              hipStream_t stream)
{
    (void)in_sizes; (void)n_in; (void)out_size; (void)ws_size;

    const float* q    = (const float*)d_in[0];
    const float* v    = (const float*)d_in[1];
    const float* Wq   = (const float*)d_in[2];
    const float* Wk   = (const float*)d_in[3];
    const float* Wv   = (const float*)d_in[4];
    const float* bt   = (const float*)d_in[5];
    const float* dw   = (const float*)d_in[6];
    const float* gam  = (const float*)d_in[7];
    const float* bet  = (const float*)d_in[8];
    const float* mean = (const float*)d_in[9];
    const float* var  = (const float*)d_in[10];
    const float* pw   = (const float*)d_in[11];
    const int*   ri   = (const int*)d_in[12];
    float* out = (float*)d_out;

    float*  qp  = (float*)d_ws;
    float*  kp  = qp + (size_t)2 * 64 * HWN;
    ushort* vp  = (ushort*)(kp + (size_t)2 * 64 * HWN);
    ushort* ao  = vp;                          // alias, see win_attn comment
    ushort* dwo = vp + (size_t)2 * 256 * HWN;

    conv1x1_64<<<512, 256, 0, stream>>>(q, Wq, qp);
    conv1x1_64<<<512, 256, 0, stream>>>(qp, Wk, kp);
    gemm256<float, ushort><<<dim3(512, 2, 2), 256, 0, stream>>>(v, Wv, vp);
    win_attn<<<16384, 64, 0, stream>>>(qp, kp, vp, ao, bt, ri);
    dwconv_bn<<<dim3(64, 256, 2), 256, 0, stream>>>(ao, dw, gam, bet, mean, var, dwo);
    gemm256<ushort, float><<<dim3(512, 2, 2), 256, 0, stream>>>(dwo, pw, out);
}

// Round 3
// 736.674 us; speedup vs baseline: 1.7194x; 1.0390x over previous
//
#include <hip/hip_runtime.h>
#include <cstddef>

#define HWN 65536              // 256*256
#define SCALE 0.35355339059327373f

typedef __bf16 bf16x8_t __attribute__((ext_vector_type(8)));
typedef float  f32x4_t  __attribute__((ext_vector_type(4)));

static __device__ __forceinline__ ushort f2bf(float f) {
    uint u = __float_as_uint(f);
    u = u + 0x7fffu + ((u >> 16) & 1u);   // RNE
    return (ushort)(u >> 16);
}
static __device__ __forceinline__ float bf2f(ushort b) {
    return __uint_as_float(((uint)b) << 16);
}

// ---------------------------------------------------------------------------
// Kernel 0: expand bias_table via rel_index into biasT[head][m][n] so the
// attention hot loop reads it with coalesced lane-contiguous loads.
// 8*64*64 floats = 128 KB; lives in the tail of d_out (dead until final GEMM).
// ---------------------------------------------------------------------------
__global__ __launch_bounds__(256) void bias_pre(
    const float* __restrict__ bt, const int* __restrict__ ri,
    float* __restrict__ biasT)
{
    int g = blockIdx.x * 256 + threadIdx.x;   // 0..32767
    int n = g & 63;
    int m = (g >> 6) & 63;
    int h = g >> 12;
    biasT[g] = bt[ri[n * 64 + m] * 8 + h];
}

// ---------------------------------------------------------------------------
// Kernel 1: 1x1 conv, 64 -> 64 channels (fp32, VALU).
// ---------------------------------------------------------------------------
__global__ __launch_bounds__(256) void conv1x1_64(
    const float* __restrict__ X, const float* __restrict__ W,
    float* __restrict__ Y)
{
    int gp = blockIdx.x * 256 + threadIdx.x;
    int b  = gp >> 16;
    int p  = gp & 65535;
    const float* Xb = X + (size_t)b * 64 * HWN + p;
    float* Yb       = Y + (size_t)b * 64 * HWN + p;

    float xr[64];
#pragma unroll
    for (int c = 0; c < 64; c++) xr[c] = Xb[(size_t)c * HWN];

#pragma unroll 4
    for (int o = 0; o < 64; o++) {
        const float* Wr = W + o * 64;
        float acc = 0.f;
#pragma unroll
        for (int c = 0; c < 64; c++) acc = fmaf(Wr[c], xr[c], acc);
        Yb[(size_t)o * HWN] = acc;
    }
}

// ---------------------------------------------------------------------------
// Kernel 2: 256->256 channel GEMM via bf16 MFMA (unchanged from R2).
// ---------------------------------------------------------------------------
template <typename XT, typename YT>
__global__ __launch_bounds__(256) void gemm256(
    const XT* __restrict__ X, const float* __restrict__ W, YT* __restrict__ Y)
{
    __shared__ ushort Al[128 * 72];   // [m][k], stride 72 bf16
    __shared__ ushort Bl[128 * 72];   // [n][k], swizzled 16B groups

    int b   = blockIdx.z;
    int oB  = blockIdx.y * 128;
    int pB  = blockIdx.x * 128;
    int tid = threadIdx.x;

    const XT* Xb = X + (size_t)b * 256 * HWN;
    YT*       Yb = Y + (size_t)b * 256 * HWN;

    int wv = tid >> 6, lane = tid & 63;
    int wm = (wv >> 1) * 64, wn = (wv & 1) * 64;
    int qd = lane >> 4, ln = lane & 15;

    int kgB = tid >> 4;
    int pgB = tid & 15;
    int p0  = pgB * 8;

    f32x4_t acc[4][4];
#pragma unroll
    for (int i = 0; i < 4; i++)
#pragma unroll
        for (int j = 0; j < 4; j++) acc[i][j] = {0.f, 0.f, 0.f, 0.f};

    for (int kc = 0; kc < 256; kc += 64) {
#pragma unroll
        for (int s = 0; s < 4; s++) {
            int u = tid + s * 256;
            int m = u >> 3, kg = u & 7;
            const float4* src = (const float4*)&W[(oB + m) * 256 + kc + kg * 8];
            float4 w0 = src[0], w1 = src[1];
            uint4 pk;
            pk.x = f2bf(w0.x) | ((uint)f2bf(w0.y) << 16);
            pk.y = f2bf(w0.z) | ((uint)f2bf(w0.w) << 16);
            pk.z = f2bf(w1.x) | ((uint)f2bf(w1.y) << 16);
            pk.w = f2bf(w1.z) | ((uint)f2bf(w1.w) << 16);
            *(uint4*)&Al[m * 72 + kg * 8] = pk;
        }
        ushort r[4][8];
#pragma unroll
        for (int i = 0; i < 4; i++) {
            int c = kc + kgB * 4 + i;
            if constexpr (sizeof(XT) == 4) {
                const float4* s = (const float4*)&Xb[(size_t)c * HWN + pB + p0];
                float4 x0 = s[0], x1 = s[1];
                r[i][0] = f2bf(x0.x); r[i][1] = f2bf(x0.y);
                r[i][2] = f2bf(x0.z); r[i][3] = f2bf(x0.w);
                r[i][4] = f2bf(x1.x); r[i][5] = f2bf(x1.y);
                r[i][6] = f2bf(x1.z); r[i][7] = f2bf(x1.w);
            } else {
                uint4 u = *(const uint4*)&Xb[(size_t)c * HWN + pB + p0];
                r[i][0] = u.x & 0xffff; r[i][1] = u.x >> 16;
                r[i][2] = u.y & 0xffff; r[i][3] = u.y >> 16;
                r[i][4] = u.z & 0xffff; r[i][5] = u.z >> 16;
                r[i][6] = u.w & 0xffff; r[i][7] = u.w >> 16;
            }
        }
        {
            int g   = kgB >> 1;
            int sub = (kgB & 1) * 4;
#pragma unroll
            for (int j = 0; j < 8; j++) {
                int n = p0 + j;
                ushort4 col = make_ushort4(r[0][j], r[1][j], r[2][j], r[3][j]);
                *(ushort4*)&Bl[n * 72 + ((g ^ (pgB & 7)) << 3) + sub] = col;
            }
        }
        __syncthreads();

#pragma unroll
        for (int ks = 0; ks < 2; ks++) {
            bf16x8_t af[4], bf[4];
#pragma unroll
            for (int i = 0; i < 4; i++)
                af[i] = *(const bf16x8_t*)&Al[(wm + i * 16 + ln) * 72 + ks * 32 + qd * 8];
#pragma unroll
            for (int j = 0; j < 4; j++) {
                int n = wn + j * 16 + ln;
                int g = ks * 4 + qd;
                bf[j] = *(const bf16x8_t*)&Bl[n * 72 + ((g ^ ((n >> 3) & 7)) << 3)];
            }
#pragma unroll
            for (int i = 0; i < 4; i++)
#pragma unroll
                for (int j = 0; j < 4; j++)
                    acc[i][j] = __builtin_amdgcn_mfma_f32_16x16x32_bf16(
                        af[i], bf[j], acc[i][j], 0, 0, 0);
        }
        __syncthreads();
    }

#pragma unroll
    for (int i = 0; i < 4; i++) {
#pragma unroll
        for (int j = 0; j < 4; j++) {
#pragma unroll
            for (int rr = 0; rr < 4; rr++) {
                int o = oB + wm + i * 16 + qd * 4 + rr;
                int p = pB + wn + j * 16 + ln;
                if constexpr (sizeof(YT) == 4)
                    Yb[(size_t)o * HWN + p] = acc[i][j][rr];
                else
                    Yb[(size_t)o * HWN + p] = f2bf(acc[i][j][rr]);
            }
        }
    }
}

// ---------------------------------------------------------------------------
// Kernel 3: windowed attention v2.  One wave per (window, head).
// QK + softmax in VALU (coalesced precomputed bias); PV via bf16 MFMA:
//   P (bf16) -> LDS rows -> A-frags; V B-frags loaded straight from global
//   (8 consecutive tokens = contiguous 16B per lane); C-layout -> LDS -> rows
//   so global stores stay coalesced.  OUT may alias VP (reads precede writes
//   within the block; blocks touch disjoint (window, head-channel) sets).
// ---------------------------------------------------------------------------
__global__ __launch_bounds__(64) void win_attn(
    const float* __restrict__ QP, const float* __restrict__ KP,
    const ushort* VP, ushort* OUT, const float* __restrict__ biasT)
{
    __shared__ float kl[64 * 8];
    __shared__ char  smem[64 * 72 * 2];        // pl (bf16) then reused as ol (f32)
    ushort* pl = (ushort*)smem;                // [n][m], stride 72
    float*  ol = (float*)smem;                 // [n][d], stride 36

    int bx   = blockIdx.x;
    int head = bx & 7;
    int win  = bx >> 3;
    int wc   = win & 31;
    int wr   = (win >> 5) & 31;
    int b    = win >> 10;

    int n   = threadIdx.x;
    int ws1 = n >> 3, ws2 = n & 7;
    int pos = (wr * 8 + ws1) * 256 + wc * 8 + ws2;

    const float*  qb = QP + ((size_t)(b * 64 + head * 8)) * HWN + pos;
    const float*  kb = KP + ((size_t)(b * 64 + head * 8)) * HWN + pos;
    const ushort* vbase = VP + ((size_t)(b * 256 + head * 32)) * HWN
                             + (size_t)(wr * 8) * 256 + wc * 8;
    ushort*       ob = OUT + ((size_t)(b * 256 + head * 32)) * HWN + pos;

    float qr[8];
#pragma unroll
    for (int d = 0; d < 8; d++) {
        qr[d] = qb[(size_t)d * HWN];
        kl[n * 8 + d] = kb[(size_t)d * HWN];
    }
    __syncthreads();

    // ---- QK^T + bias, softmax (lane n owns row n) ----
    const float* brow = biasT + head * 4096 + n;   // biasT[head][m][n]
    float attn[64];
    float mx = -1e30f;
#pragma unroll
    for (int m = 0; m < 64; m++) {
        float s = 0.f;
#pragma unroll
        for (int d = 0; d < 8; d++) s = fmaf(qr[d], kl[m * 8 + d], s);
        s = fmaf(s, SCALE, brow[m * 64]);
        attn[m] = s;
        mx = fmaxf(mx, s);
    }
    float sum = 0.f;
#pragma unroll
    for (int m = 0; m < 64; m++) {
        float e = __expf(attn[m] - mx);
        attn[m] = e;
        sum += e;
    }
    float rs = 1.f / sum;

    // ---- P -> LDS as bf16 rows ----
#pragma unroll
    for (int c = 0; c < 8; c++) {
        uint4 pk;
        pk.x = f2bf(attn[c*8+0] * rs) | ((uint)f2bf(attn[c*8+1] * rs) << 16);
        pk.y = f2bf(attn[c*8+2] * rs) | ((uint)f2bf(attn[c*8+3] * rs) << 16);
        pk.z = f2bf(attn[c*8+4] * rs) | ((uint)f2bf(attn[c*8+5] * rs) << 16);
        pk.w = f2bf(attn[c*8+6] * rs) | ((uint)f2bf(attn[c*8+7] * rs) << 16);
        *(uint4*)&pl[n * 72 + c * 8] = pk;
    }
    __syncthreads();

    // ---- PV via MFMA: O[n][d] = sum_m P[n][m] V[m][d] ----
    int ln = n & 15, qd = n >> 4;
    f32x4_t acc[4][2];
#pragma unroll
    for (int i = 0; i < 4; i++)
#pragma unroll
        for (int j = 0; j < 2; j++) acc[i][j] = {0.f, 0.f, 0.f, 0.f};

#pragma unroll
    for (int kc = 0; kc < 2; kc++) {
        bf16x8_t af[4], bf[2];
#pragma unroll
        for (int i = 0; i < 4; i++)
            af[i] = *(const bf16x8_t*)&pl[(16 * i + ln) * 72 + kc * 32 + qd * 8];
#pragma unroll
        for (int j = 0; j < 2; j++) {
            // B[d=16j+ln][k=m]: 8 consecutive tokens, contiguous 16B in global
            const ushort* vp8 = vbase + (size_t)(16 * j + ln) * HWN
                                      + (kc * 4 + qd) * 256;
            uint4 u = *(const uint4*)vp8;
            bf[j] = *(const bf16x8_t*)&u;
        }
#pragma unroll
        for (int i = 0; i < 4; i++)
#pragma unroll
            for (int j = 0; j < 2; j++)
                acc[i][j] = __builtin_amdgcn_mfma_f32_16x16x32_bf16(
                    af[i], bf[j], acc[i][j], 0, 0, 0);
    }
    __syncthreads();   // pl fully consumed; reuse smem as ol

    // ---- C-layout -> LDS -> per-lane rows, coalesced stores ----
#pragma unroll
    for (int i = 0; i < 4; i++)
#pragma unroll
        for (int j = 0; j < 2; j++)
#pragma unroll
            for (int r = 0; r < 4; r++)
                ol[(16 * i + qd * 4 + r) * 36 + j * 16 + ln] = acc[i][j][r];
    __syncthreads();

#pragma unroll
    for (int c = 0; c < 8; c++) {
        float4 o4 = *(const float4*)&ol[n * 36 + c * 4];
        ob[(size_t)(c * 4 + 0) * HWN] = f2bf(o4.x);
        ob[(size_t)(c * 4 + 1) * HWN] = f2bf(o4.y);
        ob[(size_t)(c * 4 + 2) * HWN] = f2bf(o4.z);
        ob[(size_t)(c * 4 + 3) * HWN] = f2bf(o4.w);
    }
}

// ---------------------------------------------------------------------------
// Kernel 4: reflect-pad + 8x8 depthwise conv + BN.  bf16 in/out, fp32 math.
// ---------------------------------------------------------------------------
__global__ __launch_bounds__(256) void dwconv_bn(
    const ushort* __restrict__ A, const float* __restrict__ DW,
    const float* __restrict__ gamma, const float* __restrict__ beta,
    const float* __restrict__ mean, const float* __restrict__ var,
    ushort* __restrict__ O)
{
    __shared__ float til[39 * 40];

    int c  = blockIdx.y;
    int b  = blockIdx.z;
    int tY = (blockIdx.x >> 3) * 32;
    int tX = (blockIdx.x & 7) * 32;
    int tid = threadIdx.x;

    const ushort* Ab = A + ((size_t)(b * 256 + c)) * HWN;

    for (int li = tid; li < 39 * 39; li += 256) {
        int r  = li / 39, cc = li - r * 39;
        int iy = tY - 3 + r;
        int ix = tX - 3 + cc;
        float v = 0.f;
        if (iy >= 0 && iy <= 256 && ix >= 0 && ix <= 256) {
            int sy = (iy == 256) ? 254 : iy;
            int sx = (ix == 256) ? 254 : ix;
            v = bf2f(Ab[sy * 256 + sx]);
        }
        til[r * 40 + cc] = v;
    }
    __syncthreads();

    float inv = gamma[c] * rsqrtf(var[c] + 1e-5f);
    float add = fmaf(-mean[c], inv, beta[c]);

    int sx = (tid & 7) * 4;
    int sy = tid >> 3;
    const float* dwc = DW + c * 64;

    float a0 = 0.f, a1 = 0.f, a2 = 0.f, a3 = 0.f;
#pragma unroll
    for (int ky = 0; ky < 8; ky++) {
        float row[11];
#pragma unroll
        for (int t = 0; t < 11; t++) row[t] = til[(sy + ky) * 40 + sx + t];
#pragma unroll
        for (int kx = 0; kx < 8; kx++) {
            float w = dwc[ky * 8 + kx];
            a0 = fmaf(row[kx + 0], w, a0);
            a1 = fmaf(row[kx + 1], w, a1);
            a2 = fmaf(row[kx + 2], w, a2);
            a3 = fmaf(row[kx + 3], w, a3);
        }
    }

    ushort4 r4 = make_ushort4(f2bf(fmaf(a0, inv, add)), f2bf(fmaf(a1, inv, add)),
                              f2bf(fmaf(a2, inv, add)), f2bf(fmaf(a3, inv, add)));
    *(ushort4*)&O[((size_t)(b * 256 + c)) * HWN + (tY + sy) * 256 + tX + sx] = r4;
}

// ---------------------------------------------------------------------------
// Workspace (192 MiB): qp f32 | kp f32 | vp bf16 (aliased by attn out) | dwo.
// biasT (128 KB) lives in the tail of d_out — dead until the final GEMM,
// which overwrites it after win_attn has consumed it.
// ---------------------------------------------------------------------------
extern "C" void kernel_launch(void* const* d_in, const int* in_sizes, int n_in,
                              void* d_out, int out_size, void* d_ws, size_t ws_size,
                              hipStream_t stream)
{
    (void)in_sizes; (void)n_in; (void)ws_size;

    const float* q    = (const float*)d_in[0];
    const float* v    = (const float*)d_in[1];
    const float* Wq   = (const float*)d_in[2];
    const float* Wk   = (const float*)d_in[3];
    const float* Wv   = (const float*)d_in[4];
    const float* bt   = (const float*)d_in[5];
    const float* dw   = (const float*)d_in[6];
    const float* gam  = (const float*)d_in[7];
    const float* bet  = (const float*)d_in[8];
    const float* mean = (const float*)d_in[9];
    const float* var  = (const float*)d_in[10];
    const float* pw   = (const float*)d_in[11];
    const int*   ri   = (const int*)d_in[12];
    float* out = (float*)d_out;

    float*  qp  = (float*)d_ws;
    float*  kp  = qp + (size_t)2 * 64 * HWN;
    ushort* vp  = (ushort*)(kp + (size_t)2 * 64 * HWN);
    ushort* ao  = vp;                          // alias, see win_attn comment
    ushort* dwo = vp + (size_t)2 * 256 * HWN;
    float*  biasT = out + (size_t)out_size - 32768;

    bias_pre<<<128, 256, 0, stream>>>(bt, ri, biasT);
    conv1x1_64<<<512, 256, 0, stream>>>(q, Wq, qp);
    conv1x1_64<<<512, 256, 0, stream>>>(qp, Wk, kp);
    gemm256<float, ushort><<<dim3(512, 2, 2), 256, 0, stream>>>(v, Wv, vp);
    win_attn<<<16384, 64, 0, stream>>>(qp, kp, vp, ao, biasT);
    dwconv_bn<<<dim3(64, 256, 2), 256, 0, stream>>>(ao, dw, gam, bet, mean, var, dwo);
    gemm256<ushort, float><<<dim3(512, 2, 2), 256, 0, stream>>>(dwo, pw, out);
}